// Round 13
// baseline (11792.310 us; speedup 1.0000x reference)
//
#include <hip/hip_runtime.h>

typedef _Float16 f16;
typedef _Float16 half8 __attribute__((ext_vector_type(8)));
typedef _Float16 half4v __attribute__((ext_vector_type(4)));
typedef float float4v __attribute__((ext_vector_type(4)));

constexpr int NB = 32;            // batch
constexpr int NT = 1024;          // time
constexpr int NH = 512;           // hidden
constexpr int NH3 = 1536;
constexpr int NM = NB * NT;       // 32768 rows

// h-exchange: HB[dir][buf][batch 32][colq 128] u64. One u64 = 4 consecutive f16
// h-cols of one batch; generation tag in 2 stolen LSBs (bit0 <- t&1, bit16 <- (t>>1)&1).
// One aligned 8B store => tag+data atomic. 128KB total; re-zeroed between layers
// (zeros == h0 with tag (0,0) == gen 0).
constexpr int HB_U64 = 2 * 2 * 32 * 128;   // 16384

__global__ void init_hb(unsigned long long* __restrict__ hb) {
    int i = blockIdx.x * 256 + threadIdx.x;
    if (i < HB_U64) hb[i] = 0ull;
}

// ---------------- fp32 -> fp16 convert ----------------
__global__ void cvt_f16(const float* __restrict__ src, f16* __restrict__ dst, int n4) {
    int i = blockIdx.x * blockDim.x + threadIdx.x;
    int stride = gridDim.x * blockDim.x;
    for (; i < n4; i += stride) {
        float4v v = *(const float4v*)(src + 4 * (size_t)i);
        half4v h;
        h[0] = (f16)v[0]; h[1] = (f16)v[1]; h[2] = (f16)v[2]; h[3] = (f16)v[3];
        *(half4v*)(dst + 4 * (size_t)i) = h;
    }
}

// ---------------- gi GEMM (unchanged) ----------------
__global__ __launch_bounds__(256, 2) void gemm_gi(
    const f16* __restrict__ A, const f16* __restrict__ Wf, const f16* __restrict__ Wr,
    const float* __restrict__ bf, const float* __restrict__ br,
    f16* __restrict__ gi, int K)
{
    __shared__ f16 As[128 * 72];
    __shared__ f16 Bs[128 * 72];
    const int m0 = blockIdx.x * 128;
    const int n0g = blockIdx.y * 128;
    const int dir = (n0g >= NH3) ? 1 : 0;
    const f16* __restrict__ W = dir ? Wr : Wf;
    const float* __restrict__ bias = dir ? br : bf;
    const int n0 = n0g - dir * NH3;
    const int tid = threadIdx.x;
    const int lane = tid & 63;
    const int wv = tid >> 6;
    const int wm = wv & 1;
    const int wn = wv >> 1;
    const int srow = tid >> 3;
    const int scol = (tid & 7) * 8;

    float4v acc[4][4] = {};
    for (int kb = 0; kb < K; kb += 64) {
        int4 av[4], bv[4];
#pragma unroll
        for (int i = 0; i < 4; i++) {
            av[i] = *(const int4*)(A + (size_t)(m0 + srow + i * 32) * K + kb + scol);
            bv[i] = *(const int4*)(W + (size_t)(n0 + srow + i * 32) * K + kb + scol);
        }
        __syncthreads();
#pragma unroll
        for (int i = 0; i < 4; i++) {
            *(int4*)(As + (srow + i * 32) * 72 + scol) = av[i];
            *(int4*)(Bs + (srow + i * 32) * 72 + scol) = bv[i];
        }
        __syncthreads();
#pragma unroll
        for (int ks = 0; ks < 2; ks++) {
            half8 af[4], bw[4];
#pragma unroll
            for (int i = 0; i < 4; i++) {
                af[i] = *(const half8*)(As + (wm * 64 + i * 16 + (lane & 15)) * 72 + ks * 32 + (lane >> 4) * 8);
                bw[i] = *(const half8*)(Bs + (wn * 64 + i * 16 + (lane & 15)) * 72 + ks * 32 + (lane >> 4) * 8);
            }
#pragma unroll
            for (int i = 0; i < 4; i++)
#pragma unroll
                for (int j = 0; j < 4; j++)
                    acc[i][j] = __builtin_amdgcn_mfma_f32_16x16x32_f16(af[i], bw[j], acc[i][j], 0, 0, 0);
        }
    }
    f16* __restrict__ gid = gi + (size_t)dir * NM * NH3;
#pragma unroll
    for (int i = 0; i < 4; i++) {
        const int m = m0 + wm * 64 + i * 16 + ((lane >> 4) << 2);
#pragma unroll
        for (int j = 0; j < 4; j++) {
            const int n = n0 + wn * 64 + j * 16 + (lane & 15);
            const float b = bias[n];
#pragma unroll
            for (int r = 0; r < 4; r++)
                gid[(size_t)(m + r) * NH3 + n] = (f16)(acc[i][j][r] + b);
        }
    }
}

// ---------------- device-coherent helpers ----------------
__device__ __forceinline__ unsigned long long ld_dev_u64(const void* p) {
    return __hip_atomic_load((const unsigned long long*)p,
                             __ATOMIC_RELAXED, __HIP_MEMORY_SCOPE_AGENT);
}
__device__ __forceinline__ void st_dev_u64(void* p, unsigned long long v) {
    __hip_atomic_store((unsigned long long*)p, v,
                       __ATOMIC_RELAXED, __HIP_MEMORY_SCOPE_AGENT);
}

union U2H8 { unsigned long long u[2]; half8 h; };
union U1H4 { unsigned long long u; half4v h; };

// ---------------- GRU scan ----------------
// R11 transposed-MFMA base: 64 blocks (dir x 16-col slice), 128 threads. Each lane
// owns (batch bP, 4 consecutive cols cP..cP+3); publish = ONE tagged u64 store.
// R13: deferred y-burst done RIGHT -- t-loop restructured as 128 x (unroll 8) so
// yreg[j] has compile-time indices (stays in VGPRs; R12's yreg[t&7] went to scratch,
// rule #20). 7 of 8 polls now have no y-stores outstanding for their implicit
// vmcnt(0) to drain. All tag patterns become compile-time constants per j.
__global__ __launch_bounds__(128, 1) void gru_scan(
    const f16* __restrict__ gi,      // [2][NM][1536]
    const f16* __restrict__ Whf, const f16* __restrict__ Whr,   // [1536][512]
    const float* __restrict__ bhf, const float* __restrict__ bhr,
    unsigned long long* __restrict__ HB,   // [2][2][32][128] u64
    f16* __restrict__ y16,           // layer0 output (fp16) or nullptr
    float* __restrict__ y32,         // layer1 output (fp32, d_out) or nullptr
    float* __restrict__ hlast)       // [2][NB][NH] fp32
{
    __shared__ f16 Wlds[48 * 520];
    const int d = blockIdx.x >> 5;
    const int cs = blockIdx.x & 31;
    const int c0 = cs * 16;
    const f16* __restrict__ W = d ? Whr : Whf;
    const float* __restrict__ bhh = d ? bhr : bhf;
    const int tid = threadIdx.x;
    const int lane = tid & 63;
    const int mt = tid >> 6;         // wave index = batch half

    // stage W_hh rows {g*512 + c0 + j} into LDS (row-major [48][520], padded)
    for (int c = tid; c < 48 * 64; c += 128) {
        const int row = c >> 6;
        const int off = (c & 63) * 8;
        const int g = row >> 4, j = row & 15;
        *(int4*)(Wlds + row * 520 + off) = *(const int4*)(W + (size_t)(g * 512 + c0 + j) * 512 + off);
    }
    __syncthreads();

    // W fragments (A-operand): lane holds W[c0 + (lane&15)][k-slice]
    half8 bfr[16][3];
#pragma unroll
    for (int kk = 0; kk < 16; kk++)
#pragma unroll
        for (int g = 0; g < 3; g++)
            bfr[kk][g] = *(const half8*)(Wlds + (g * 16 + (lane & 15)) * 520 + kk * 32 + (lane >> 4) * 8);

    const int bP = mt * 16 + (lane & 15);   // owned batch (B-col = C-col)
    const int q  = lane >> 4;               // col-quad 0..3
    const int cP = c0 + q * 4;              // first owned output col (C-rows q*4+r)

    float bh[3][4];
#pragma unroll
    for (int g = 0; g < 3; g++) {
        const float4v bv = *(const float4v*)(bhh + g * 512 + cP);
#pragma unroll
        for (int r = 0; r < 4; r++) bh[g][r] = bv[r];
    }

    const f16* __restrict__ giD = gi + (size_t)d * NM * NH3;
    unsigned long long* const HBd = HB + (size_t)d * 2 * 32 * 128;
    const unsigned long long* const HBrow0 = HBd + (size_t)bP * 128;            // buf 0
    const unsigned long long* const HBrow1 = HBd + 32 * 128 + (size_t)bP * 128; // buf 1

    float h32[4] = {0.f, 0.f, 0.f, 0.f};
    half4v gih[3];                    // gi for current step (packed f16)
    {
        const int te = d ? (NT - 1) : 0;
        const f16* p = giD + ((size_t)bP * NT + te) * NH3 + cP;
#pragma unroll
        for (int g = 0; g < 3; g++) gih[g] = *(const half4v*)(p + g * 512);
    }

    for (int t8 = 0; t8 < NT / 8; t8++) {
        unsigned long long yreg[8];   // compile-time-indexed only (stays in VGPRs)
#pragma unroll
        for (int j = 0; j < 8; j++) {
            const int t = t8 * 8 + j;
            // compile-time tag pattern: t&1 == j&1, (t>>1)&1 == (j>>1)&1 (t8*8 ≡ 0 mod 4)
            const unsigned long long tagpat =
                (unsigned long long)(unsigned)(j & 1) |
                ((unsigned long long)(unsigned)((j >> 1) & 1) << 16);
            const unsigned long long* const HBr = (j & 1) ? HBrow1 : HBrow0;

            // -------- poll: 32 u64 (own batch row) until all tags match gen t ------
            unsigned long long ch[16][2];
            bool ok;
            do {
#pragma unroll
                for (int kk = 0; kk < 16; kk++) {
                    ch[kk][0] = ld_dev_u64(HBr + kk * 8 + q * 2);
                    ch[kk][1] = ld_dev_u64(HBr + kk * 8 + q * 2 + 1);
                }
                unsigned long long bad = 0;
#pragma unroll
                for (int kk = 0; kk < 16; kk++)
#pragma unroll
                    for (int c = 0; c < 2; c++)
                        bad |= (ch[kk][c] ^ tagpat) & 0x0000000000010001ull;
                ok = __all(bad == 0);
            } while (!ok);

            // -------- early gi prefetch for t+1 (retired before next poll) --------
            const bool more = (t + 1 < NT);
            half4v gin[3];
            if (more) {
                const int te2 = d ? (NT - 2 - t) : (t + 1);
                const f16* p = giD + ((size_t)bP * NT + te2) * NH3 + cP;
#pragma unroll
                for (int g = 0; g < 3; g++) gin[g] = *(const half4v*)(p + g * 512);
            }

            // -------- fragments (zero-ALU bitcast) + transposed MFMA --------
            float4v acc[3] = {};
#pragma unroll
            for (int kk = 0; kk < 16; kk++) {
                U2H8 u;
                u.u[0] = ch[kk][0];
                u.u[1] = ch[kk][1];
#pragma unroll
                for (int g = 0; g < 3; g++)
                    acc[g] = __builtin_amdgcn_mfma_f32_16x16x32_f16(bfr[kk][g], u.h, acc[g], 0, 0, 0);
            }

            float hnew[4]; f16 hnew16[4];
#pragma unroll
            for (int r = 0; r < 4; r++) {
                const float hr = acc[0][r] + bh[0][r];
                const float hz = acc[1][r] + bh[1][r];
                const float hn = acc[2][r] + bh[2][r];
                const float rg = 1.f / (1.f + __expf(-((float)gih[0][r] + hr)));
                const float zg = 1.f / (1.f + __expf(-((float)gih[1][r] + hz)));
                const float x2 = (float)gih[2][r] + rg * hn;
                const float e2 = __expf(x2 + x2);
                const float ng = 1.f - 2.f / (e2 + 1.f);
                const float h = (1.f - zg) * ng + zg * h32[r];
                h32[r] = h; hnew[r] = h; hnew16[r] = (f16)h;
            }

            const unsigned long long pk0 =
                (unsigned long long)__builtin_bit_cast(unsigned short, hnew16[0]) |
                ((unsigned long long)__builtin_bit_cast(unsigned short, hnew16[1]) << 16) |
                ((unsigned long long)__builtin_bit_cast(unsigned short, hnew16[2]) << 32) |
                ((unsigned long long)__builtin_bit_cast(unsigned short, hnew16[3]) << 48);

            if (more) {
                // -------- publish: ONE tagged u64 store, immediately --------
                // (t+1) tags: (j+1)&1 and ((j+1)>>1)&1 are compile-time (j=7 -> 0,0)
                const unsigned long long ntag =
                    (unsigned long long)(unsigned)((j + 1) & 1) |
                    ((unsigned long long)(unsigned)(((j + 1) >> 1) & 1) << 16);
                const unsigned long long pk = (pk0 & ~0x0000000000010001ull) | ntag;
                unsigned long long* const HBw = (unsigned long long*)
                    (((j + 1) & 1) ? HBrow1 : HBrow0);
                st_dev_u64(HBw + (cP >> 2), pk);
            }

            yreg[j] = pk0;            // register-resident (static index)

#pragma unroll
            for (int g = 0; g < 3; g++) gih[g] = gin[g];
        }

        // -------- y burst: 8 steps' outputs, once per 8 steps --------
        {
            const int tb0 = t8 * 8;
#pragma unroll
            for (int j = 0; j < 8; j++) {
                const int tj = tb0 + j;
                const int tej = d ? (NT - 1 - tj) : tj;
                const size_t yoff = ((size_t)bP * NT + tej) * (2 * NH) + d * NH + cP;
                if (y16) {
                    __builtin_nontemporal_store(yreg[j], (unsigned long long*)(y16 + yoff));
                } else {
                    U1H4 u; u.u = yreg[j];
                    float4v yv;
#pragma unroll
                    for (int r = 0; r < 4; r++) yv[r] = (float)u.h[r];
                    __builtin_nontemporal_store(yv, (float4v*)(y32 + yoff));
                }
            }
        }
    }

    // final hidden state (h32 holds h at t = NT-1)
    {
        float4v hv; hv[0] = h32[0]; hv[1] = h32[1]; hv[2] = h32[2]; hv[3] = h32[3];
        *(float4v*)(hlast + d * NB * NH + bP * NH + cP) = hv;
    }
}

extern "C" void kernel_launch(void* const* d_in, const int* in_sizes, int n_in,
                              void* d_out, int out_size, void* d_ws, size_t ws_size,
                              hipStream_t stream) {
    (void)in_sizes; (void)n_in; (void)out_size; (void)ws_size;
    const float* X     = (const float*)d_in[0];
    const float* wih0f = (const float*)d_in[1];
    const float* bih0f = (const float*)d_in[2];
    const float* whh0f = (const float*)d_in[3];
    const float* bhh0f = (const float*)d_in[4];
    const float* wih0r = (const float*)d_in[5];
    const float* bih0r = (const float*)d_in[6];
    const float* whh0r = (const float*)d_in[7];
    const float* bhh0r = (const float*)d_in[8];
    const float* wih1f = (const float*)d_in[9];
    const float* bih1f = (const float*)d_in[10];
    const float* whh1f = (const float*)d_in[11];
    const float* bhh1f = (const float*)d_in[12];
    const float* wih1r = (const float*)d_in[13];
    const float* bih1r = (const float*)d_in[14];
    const float* whh1r = (const float*)d_in[15];
    const float* bhh1r = (const float*)d_in[16];

    char* ws = (char*)d_ws;
    f16* Xh   = (f16*)(ws + 0ull);
    f16* Wi0f = (f16*)(ws + 33554432ull);
    f16* Wi0r = (f16*)(ws + 35127296ull);
    f16* Wh0f = (f16*)(ws + 36700160ull);
    f16* Wh0r = (f16*)(ws + 38273024ull);
    f16* Wi1f = (f16*)(ws + 39845888ull);
    f16* Wi1r = (f16*)(ws + 42991616ull);
    f16* Wh1f = (f16*)(ws + 46137344ull);
    f16* Wh1r = (f16*)(ws + 47710208ull);
    f16* Y0h  = (f16*)(ws + 49283072ull);
    unsigned long long* HBu = (unsigned long long*)(ws + 116391936ull);  // 128KB
    f16* GI   = (f16*)(ws + 116655104ull);
    float* out = (float*)d_out;

    auto cvt = [&](const float* s, f16* d, size_t n) {
        int n4 = (int)(n / 4);
        int grid = (n4 + 255) / 256; if (grid > 4096) grid = 4096;
        cvt_f16<<<grid, 256, 0, stream>>>(s, d, n4);
    };
    cvt(X,     Xh,   (size_t)NM * NH);
    cvt(wih0f, Wi0f, (size_t)NH3 * NH);
    cvt(wih0r, Wi0r, (size_t)NH3 * NH);
    cvt(whh0f, Wh0f, (size_t)NH3 * NH);
    cvt(whh0r, Wh0r, (size_t)NH3 * NH);
    cvt(wih1f, Wi1f, (size_t)NH3 * 2 * NH);
    cvt(wih1r, Wi1r, (size_t)NH3 * 2 * NH);
    cvt(whh1f, Wh1f, (size_t)NH3 * NH);
    cvt(whh1r, Wh1r, (size_t)NH3 * NH);

    const size_t OUT0 = (size_t)NM * 2 * NH;   // 33,554,432 floats

    // Layer 0
    init_hb<<<64, 256, 0, stream>>>(HBu);
    gemm_gi<<<dim3(NM / 128, 24), 256, 0, stream>>>(Xh, Wi0f, Wi0r, bih0f, bih0r, GI, NH);
    gru_scan<<<64, 128, 0, stream>>>(GI, Wh0f, Wh0r, bhh0f, bhh0r,
                                     HBu, Y0h, nullptr, out + OUT0);
    // Layer 1 (reset tags to gen 0, reuse HB)
    init_hb<<<64, 256, 0, stream>>>(HBu);
    gemm_gi<<<dim3(NM / 128, 24), 256, 0, stream>>>(Y0h, Wi1f, Wi1r, bih1f, bih1r, GI, 2 * NH);
    gru_scan<<<64, 128, 0, stream>>>(GI, Wh1f, Wh1r, bhh1f, bhh1r,
                                     HBu, nullptr, out, out + OUT0 + 2 * NB * NH);
}

// Round 14
// 8121.293 us; speedup vs baseline: 1.4520x; 1.4520x over previous
//
#include <hip/hip_runtime.h>

typedef _Float16 f16;
typedef _Float16 half8 __attribute__((ext_vector_type(8)));
typedef _Float16 half4v __attribute__((ext_vector_type(4)));
typedef float float4v __attribute__((ext_vector_type(4)));

constexpr int NB = 32;            // batch
constexpr int NT = 1024;          // time
constexpr int NH = 512;           // hidden
constexpr int NH3 = 1536;
constexpr int NM = NB * NT;       // 32768 rows

// h-exchange: HB[dir][buf][batch 32][colq 128] u64. One u64 = 4 consecutive f16
// h-cols of one batch; generation tag in 2 stolen LSBs (bit0 <- t&1, bit16 <- (t>>1)&1).
// One aligned 8B store => tag+data atomic. 128KB total; re-zeroed between layers
// (zeros == h0 with tag (0,0) == gen 0).
constexpr int HB_U64 = 2 * 2 * 32 * 128;   // 16384

__global__ void init_hb(unsigned long long* __restrict__ hb) {
    int i = blockIdx.x * 256 + threadIdx.x;
    if (i < HB_U64) hb[i] = 0ull;
}

// ---------------- fp32 -> fp16 convert ----------------
__global__ void cvt_f16(const float* __restrict__ src, f16* __restrict__ dst, int n4) {
    int i = blockIdx.x * blockDim.x + threadIdx.x;
    int stride = gridDim.x * blockDim.x;
    for (; i < n4; i += stride) {
        float4v v = *(const float4v*)(src + 4 * (size_t)i);
        half4v h;
        h[0] = (f16)v[0]; h[1] = (f16)v[1]; h[2] = (f16)v[2]; h[3] = (f16)v[3];
        *(half4v*)(dst + 4 * (size_t)i) = h;
    }
}

// ---------------- gi GEMM (unchanged) ----------------
__global__ __launch_bounds__(256, 2) void gemm_gi(
    const f16* __restrict__ A, const f16* __restrict__ Wf, const f16* __restrict__ Wr,
    const float* __restrict__ bf, const float* __restrict__ br,
    f16* __restrict__ gi, int K)
{
    __shared__ f16 As[128 * 72];
    __shared__ f16 Bs[128 * 72];
    const int m0 = blockIdx.x * 128;
    const int n0g = blockIdx.y * 128;
    const int dir = (n0g >= NH3) ? 1 : 0;
    const f16* __restrict__ W = dir ? Wr : Wf;
    const float* __restrict__ bias = dir ? br : bf;
    const int n0 = n0g - dir * NH3;
    const int tid = threadIdx.x;
    const int lane = tid & 63;
    const int wv = tid >> 6;
    const int wm = wv & 1;
    const int wn = wv >> 1;
    const int srow = tid >> 3;
    const int scol = (tid & 7) * 8;

    float4v acc[4][4] = {};
    for (int kb = 0; kb < K; kb += 64) {
        int4 av[4], bv[4];
#pragma unroll
        for (int i = 0; i < 4; i++) {
            av[i] = *(const int4*)(A + (size_t)(m0 + srow + i * 32) * K + kb + scol);
            bv[i] = *(const int4*)(W + (size_t)(n0 + srow + i * 32) * K + kb + scol);
        }
        __syncthreads();
#pragma unroll
        for (int i = 0; i < 4; i++) {
            *(int4*)(As + (srow + i * 32) * 72 + scol) = av[i];
            *(int4*)(Bs + (srow + i * 32) * 72 + scol) = bv[i];
        }
        __syncthreads();
#pragma unroll
        for (int ks = 0; ks < 2; ks++) {
            half8 af[4], bw[4];
#pragma unroll
            for (int i = 0; i < 4; i++) {
                af[i] = *(const half8*)(As + (wm * 64 + i * 16 + (lane & 15)) * 72 + ks * 32 + (lane >> 4) * 8);
                bw[i] = *(const half8*)(Bs + (wn * 64 + i * 16 + (lane & 15)) * 72 + ks * 32 + (lane >> 4) * 8);
            }
#pragma unroll
            for (int i = 0; i < 4; i++)
#pragma unroll
                for (int j = 0; j < 4; j++)
                    acc[i][j] = __builtin_amdgcn_mfma_f32_16x16x32_f16(af[i], bw[j], acc[i][j], 0, 0, 0);
        }
    }
    f16* __restrict__ gid = gi + (size_t)dir * NM * NH3;
#pragma unroll
    for (int i = 0; i < 4; i++) {
        const int m = m0 + wm * 64 + i * 16 + ((lane >> 4) << 2);
#pragma unroll
        for (int j = 0; j < 4; j++) {
            const int n = n0 + wn * 64 + j * 16 + (lane & 15);
            const float b = bias[n];
#pragma unroll
            for (int r = 0; r < 4; r++)
                gid[(size_t)(m + r) * NH3 + n] = (f16)(acc[i][j][r] + b);
        }
    }
}

// ---------------- device-coherent helpers ----------------
__device__ __forceinline__ unsigned long long ld_dev_u64(const void* p) {
    return __hip_atomic_load((const unsigned long long*)p,
                             __ATOMIC_RELAXED, __HIP_MEMORY_SCOPE_AGENT);
}
__device__ __forceinline__ void st_dev_u64(void* p, unsigned long long v) {
    __hip_atomic_store((unsigned long long*)p, v,
                       __ATOMIC_RELAXED, __HIP_MEMORY_SCOPE_AGENT);
}

union U2H8 { unsigned long long u[2]; half8 h; };

// ---------------- GRU scan ----------------
// R11 (proven best): 64 blocks (blockIdx/32 = dir, blockIdx%32 = 16-col slice),
// 128 threads (2 waves). TRANSPOSED MFMA: A-operand = W rows (16 output cols),
// B-operand = h (16 batches) -> each lane owns 4 CONSECUTIVE output cols x 1 batch
// = exactly one u64 of 4 f16: publish = single coherent store, no LDS transpose,
// no barrier. Tag = 2 stolen LSBs (mod-4 generation; only possible stale occupant
// is gen t-2, which always differs in bit16). Consumer fragments are a zero-ALU
// bitcast of 2 u64s; detection completes WITH the data in registers (1 coherent RT).
__global__ __launch_bounds__(128, 1) void gru_scan(
    const f16* __restrict__ gi,      // [2][NM][1536]
    const f16* __restrict__ Whf, const f16* __restrict__ Whr,   // [1536][512]
    const float* __restrict__ bhf, const float* __restrict__ bhr,
    unsigned long long* __restrict__ HB,   // [2][2][32][128] u64
    f16* __restrict__ y16,           // layer0 output (fp16) or nullptr
    float* __restrict__ y32,         // layer1 output (fp32, d_out) or nullptr
    float* __restrict__ hlast)       // [2][NB][NH] fp32
{
    __shared__ f16 Wlds[48 * 520];
    const int d = blockIdx.x >> 5;
    const int cs = blockIdx.x & 31;
    const int c0 = cs * 16;
    const f16* __restrict__ W = d ? Whr : Whf;
    const float* __restrict__ bhh = d ? bhr : bhf;
    const int tid = threadIdx.x;
    const int lane = tid & 63;
    const int mt = tid >> 6;         // wave index = batch half

    // stage W_hh rows {g*512 + c0 + j} into LDS (row-major [48][520], padded)
    for (int c = tid; c < 48 * 64; c += 128) {
        const int row = c >> 6;
        const int off = (c & 63) * 8;
        const int g = row >> 4, j = row & 15;
        *(int4*)(Wlds + row * 520 + off) = *(const int4*)(W + (size_t)(g * 512 + c0 + j) * 512 + off);
    }
    __syncthreads();

    // W fragments (A-operand): lane holds W[c0 + (lane&15)][k-slice]
    half8 bfr[16][3];
#pragma unroll
    for (int kk = 0; kk < 16; kk++)
#pragma unroll
        for (int g = 0; g < 3; g++)
            bfr[kk][g] = *(const half8*)(Wlds + (g * 16 + (lane & 15)) * 520 + kk * 32 + (lane >> 4) * 8);

    const int bP = mt * 16 + (lane & 15);   // owned batch (B-col = C-col)
    const int q  = lane >> 4;               // col-quad 0..3
    const int cP = c0 + q * 4;              // first owned output col (C-rows q*4+r)

    float bh[3][4];
#pragma unroll
    for (int g = 0; g < 3; g++) {
        const float4v bv = *(const float4v*)(bhh + g * 512 + cP);
#pragma unroll
        for (int r = 0; r < 4; r++) bh[g][r] = bv[r];
    }

    const f16* __restrict__ giD = gi + (size_t)d * NM * NH3;
    unsigned long long* const HBd = HB + (size_t)d * 2 * 32 * 128;

    float h32[4] = {0.f, 0.f, 0.f, 0.f};
    float gif[3][4];
    {
        const int te = d ? (NT - 1) : 0;
        const f16* p = giD + ((size_t)bP * NT + te) * NH3 + cP;
#pragma unroll
        for (int g = 0; g < 3; g++) {
            const half4v v = *(const half4v*)(p + g * 512);
#pragma unroll
            for (int r = 0; r < 4; r++) gif[g][r] = (float)v[r];
        }
    }

    for (int t = 0; t < NT; t++) {
        const int te = d ? (NT - 1 - t) : t;
        const unsigned long long* const HBr =
            HBd + (size_t)(t & 1) * 32 * 128 + (size_t)bP * 128;
        const unsigned long long tagpat =
            (unsigned long long)((unsigned)(t & 1)) |
            ((unsigned long long)((unsigned)((t >> 1) & 1)) << 16);

        // -------- poll: 32 u64 (own batch row) until all tag bits match gen t ------
        unsigned long long ch[16][2];
        bool ok;
        do {
#pragma unroll
            for (int kk = 0; kk < 16; kk++) {
                ch[kk][0] = ld_dev_u64(HBr + kk * 8 + q * 2);
                ch[kk][1] = ld_dev_u64(HBr + kk * 8 + q * 2 + 1);
            }
            unsigned long long bad = 0;
#pragma unroll
            for (int kk = 0; kk < 16; kk++)
#pragma unroll
                for (int c = 0; c < 2; c++)
                    bad |= (ch[kk][c] ^ tagpat) & 0x0000000000010001ull;
            ok = __all(bad == 0);
        } while (!ok);

        // -------- fragments (zero-ALU bitcast) + transposed MFMA --------
        float4v acc[3] = {};
#pragma unroll
        for (int kk = 0; kk < 16; kk++) {
            U2H8 u;
            u.u[0] = ch[kk][0];
            u.u[1] = ch[kk][1];
#pragma unroll
            for (int g = 0; g < 3; g++)
                acc[g] = __builtin_amdgcn_mfma_f32_16x16x32_f16(bfr[kk][g], u.h, acc[g], 0, 0, 0);
        }

        float hnew[4]; f16 hnew16[4];
#pragma unroll
        for (int r = 0; r < 4; r++) {
            const float hr = acc[0][r] + bh[0][r];
            const float hz = acc[1][r] + bh[1][r];
            const float hn = acc[2][r] + bh[2][r];
            const float rg = 1.f / (1.f + __expf(-(gif[0][r] + hr)));
            const float zg = 1.f / (1.f + __expf(-(gif[1][r] + hz)));
            const float x2 = gif[2][r] + rg * hn;
            const float e2 = __expf(x2 + x2);
            const float ng = 1.f - 2.f / (e2 + 1.f);
            const float h = (1.f - zg) * ng + zg * h32[r];
            h32[r] = h; hnew[r] = h; hnew16[r] = (f16)h;
        }

        const bool more = (t + 1 < NT);
        if (more) {
            // -------- publish: ONE tagged u64 store per thread, immediately --------
            unsigned long long pk =
                (unsigned long long)__builtin_bit_cast(unsigned short, hnew16[0]) |
                ((unsigned long long)__builtin_bit_cast(unsigned short, hnew16[1]) << 16) |
                ((unsigned long long)__builtin_bit_cast(unsigned short, hnew16[2]) << 32) |
                ((unsigned long long)__builtin_bit_cast(unsigned short, hnew16[3]) << 48);
            pk = (pk & ~0x0000000000010001ull) |
                 (unsigned long long)((unsigned)((t + 1) & 1)) |
                 ((unsigned long long)((unsigned)(((t + 1) >> 1) & 1)) << 16);
            st_dev_u64(HBd + (size_t)((t + 1) & 1) * 32 * 128 + (size_t)bP * 128 + (cP >> 2), pk);
        }
        // -------- y output (clean values, vectorized nontemporal) --------
        {
            const size_t yoff = ((size_t)bP * NT + te) * (2 * NH) + d * NH + cP;
            if (y16) {
                const unsigned long long yv =
                    (unsigned long long)__builtin_bit_cast(unsigned short, hnew16[0]) |
                    ((unsigned long long)__builtin_bit_cast(unsigned short, hnew16[1]) << 16) |
                    ((unsigned long long)__builtin_bit_cast(unsigned short, hnew16[2]) << 32) |
                    ((unsigned long long)__builtin_bit_cast(unsigned short, hnew16[3]) << 48);
                __builtin_nontemporal_store(yv, (unsigned long long*)(y16 + yoff));
            } else {
                float4v yv; yv[0] = hnew[0]; yv[1] = hnew[1]; yv[2] = hnew[2]; yv[3] = hnew[3];
                __builtin_nontemporal_store(yv, (float4v*)(y32 + yoff));
            }
        }
        if (t == NT - 1) {
            float4v hv; hv[0] = hnew[0]; hv[1] = hnew[1]; hv[2] = hnew[2]; hv[3] = hnew[3];
            *(float4v*)(hlast + d * NB * NH + bP * NH + cP) = hv;
        }
        if (more) {
            // prefetch gi for t+1 (plain cached; in flight during next poll)
            const int te2 = d ? (NT - 2 - t) : (t + 1);
            const f16* p = giD + ((size_t)bP * NT + te2) * NH3 + cP;
#pragma unroll
            for (int g = 0; g < 3; g++) {
                const half4v v = *(const half4v*)(p + g * 512);
#pragma unroll
                for (int r = 0; r < 4; r++) gif[g][r] = (float)v[r];
            }
        }
    }
}

extern "C" void kernel_launch(void* const* d_in, const int* in_sizes, int n_in,
                              void* d_out, int out_size, void* d_ws, size_t ws_size,
                              hipStream_t stream) {
    (void)in_sizes; (void)n_in; (void)out_size; (void)ws_size;
    const float* X     = (const float*)d_in[0];
    const float* wih0f = (const float*)d_in[1];
    const float* bih0f = (const float*)d_in[2];
    const float* whh0f = (const float*)d_in[3];
    const float* bhh0f = (const float*)d_in[4];
    const float* wih0r = (const float*)d_in[5];
    const float* bih0r = (const float*)d_in[6];
    const float* whh0r = (const float*)d_in[7];
    const float* bhh0r = (const float*)d_in[8];
    const float* wih1f = (const float*)d_in[9];
    const float* bih1f = (const float*)d_in[10];
    const float* whh1f = (const float*)d_in[11];
    const float* bhh1f = (const float*)d_in[12];
    const float* wih1r = (const float*)d_in[13];
    const float* bih1r = (const float*)d_in[14];
    const float* whh1r = (const float*)d_in[15];
    const float* bhh1r = (const float*)d_in[16];

    char* ws = (char*)d_ws;
    f16* Xh   = (f16*)(ws + 0ull);
    f16* Wi0f = (f16*)(ws + 33554432ull);
    f16* Wi0r = (f16*)(ws + 35127296ull);
    f16* Wh0f = (f16*)(ws + 36700160ull);
    f16* Wh0r = (f16*)(ws + 38273024ull);
    f16* Wi1f = (f16*)(ws + 39845888ull);
    f16* Wi1r = (f16*)(ws + 42991616ull);
    f16* Wh1f = (f16*)(ws + 46137344ull);
    f16* Wh1r = (f16*)(ws + 47710208ull);
    f16* Y0h  = (f16*)(ws + 49283072ull);
    unsigned long long* HBu = (unsigned long long*)(ws + 116391936ull);  // 128KB
    f16* GI   = (f16*)(ws + 116655104ull);
    float* out = (float*)d_out;

    auto cvt = [&](const float* s, f16* d, size_t n) {
        int n4 = (int)(n / 4);
        int grid = (n4 + 255) / 256; if (grid > 4096) grid = 4096;
        cvt_f16<<<grid, 256, 0, stream>>>(s, d, n4);
    };
    cvt(X,     Xh,   (size_t)NM * NH);
    cvt(wih0f, Wi0f, (size_t)NH3 * NH);
    cvt(wih0r, Wi0r, (size_t)NH3 * NH);
    cvt(whh0f, Wh0f, (size_t)NH3 * NH);
    cvt(whh0r, Wh0r, (size_t)NH3 * NH);
    cvt(wih1f, Wi1f, (size_t)NH3 * 2 * NH);
    cvt(wih1r, Wi1r, (size_t)NH3 * 2 * NH);
    cvt(whh1f, Wh1f, (size_t)NH3 * NH);
    cvt(whh1r, Wh1r, (size_t)NH3 * NH);

    const size_t OUT0 = (size_t)NM * 2 * NH;   // 33,554,432 floats

    // Layer 0
    init_hb<<<64, 256, 0, stream>>>(HBu);
    gemm_gi<<<dim3(NM / 128, 24), 256, 0, stream>>>(Xh, Wi0f, Wi0r, bih0f, bih0r, GI, NH);
    gru_scan<<<64, 128, 0, stream>>>(GI, Wh0f, Wh0r, bhh0f, bhh0r,
                                     HBu, Y0h, nullptr, out + OUT0);
    // Layer 1 (reset tags to gen 0, reuse HB)
    init_hb<<<64, 256, 0, stream>>>(HBu);
    gemm_gi<<<dim3(NM / 128, 24), 256, 0, stream>>>(Y0h, Wi1f, Wi1r, bih1f, bih1r, GI, 2 * NH);
    gru_scan<<<64, 128, 0, stream>>>(GI, Wh1f, Wh1r, bhh1f, bhh1r,
                                     HBu, nullptr, out, out + OUT0 + 2 * NB * NH);
}

// Round 15
// 6624.485 us; speedup vs baseline: 1.7801x; 1.2260x over previous
//
#include <hip/hip_runtime.h>

typedef _Float16 f16;
typedef _Float16 half8 __attribute__((ext_vector_type(8)));
typedef _Float16 half4v __attribute__((ext_vector_type(4)));
typedef float float4v __attribute__((ext_vector_type(4)));

constexpr int NB = 32;            // batch
constexpr int NT = 1024;          // time
constexpr int NH = 512;           // hidden
constexpr int NH3 = 1536;
constexpr int NM = NB * NT;       // 32768 rows

// h-exchange: HB[dir][buf][batch 32][colq 128] u64. One u64 = 4 consecutive f16
// h-cols of one batch; generation tag in 2 stolen LSBs (bit0 <- t&1, bit16 <- (t>>1)&1).
// One aligned 8B store => tag+data atomic. 128KB total; re-zeroed between layers
// (zeros == h0 with tag (0,0) == gen 0).
constexpr int HB_U64 = 2 * 2 * 32 * 128;   // 16384

__global__ void init_hb(unsigned long long* __restrict__ hb) {
    int i = blockIdx.x * 256 + threadIdx.x;
    if (i < HB_U64) hb[i] = 0ull;
}

// ---------------- fp32 -> fp16 convert ----------------
__global__ void cvt_f16(const float* __restrict__ src, f16* __restrict__ dst, int n4) {
    int i = blockIdx.x * blockDim.x + threadIdx.x;
    int stride = gridDim.x * blockDim.x;
    for (; i < n4; i += stride) {
        float4v v = *(const float4v*)(src + 4 * (size_t)i);
        half4v h;
        h[0] = (f16)v[0]; h[1] = (f16)v[1]; h[2] = (f16)v[2]; h[3] = (f16)v[3];
        *(half4v*)(dst + 4 * (size_t)i) = h;
    }
}

// ---------------- gi GEMM: R15 = global_load_lds w16 staging (m97 structure) -------
// Linear LDS tiles + XOR swizzle (rule #21: linear dest + pre-swizzled global source
// + same XOR on ds_read). cb ^= (row&7)<<4 spreads 8 consecutive rows across all 32
// banks (2-way residual = free). Fragment data bit-identical to the old padded
// layout -> MFMA/epilogue semantics unchanged.
__global__ __launch_bounds__(256, 2) void gemm_gi(
    const f16* __restrict__ A, const f16* __restrict__ Wf, const f16* __restrict__ Wr,
    const float* __restrict__ bf, const float* __restrict__ br,
    f16* __restrict__ gi, int K)
{
    __shared__ f16 As[128 * 64];   // linear [row][64] f16, swizzled content
    __shared__ f16 Bs[128 * 64];
    const int m0 = blockIdx.x * 128;
    const int n0g = blockIdx.y * 128;
    const int dir = (n0g >= NH3) ? 1 : 0;
    const f16* __restrict__ W = dir ? Wr : Wf;
    const float* __restrict__ bias = dir ? br : bf;
    const int n0 = n0g - dir * NH3;
    const int tid = threadIdx.x;
    const int lane = tid & 63;
    const int wv = tid >> 6;
    const int wm = wv & 1;
    const int wn = wv >> 1;

    float4v acc[4][4] = {};
    for (int kb = 0; kb < K; kb += 64) {
        // ---- stage A,B tiles: 8 x global_load_lds(16B), wave-uniform LDS base +
        // lane*16 (chunk = s*256 + tid). Source col pre-swizzled. ----
#pragma unroll
        for (int s = 0; s < 4; s++) {
            const int chunk = s * 256 + tid;        // 16B chunk id, 0..1023
            const int row = chunk >> 3;             // tile row 0..127
            const int scb = ((chunk & 7) * 16) ^ ((row & 7) << 4);
            __builtin_amdgcn_global_load_lds(
                (const void*)((const char*)(A + (size_t)(m0 + row) * K + kb) + scb),
                (void*)((char*)As + chunk * 16), 16, 0, 0);
            __builtin_amdgcn_global_load_lds(
                (const void*)((const char*)(W + (size_t)(n0 + row) * K + kb) + scb),
                (void*)((char*)Bs + chunk * 16), 16, 0, 0);
        }
        __syncthreads();   // vmcnt drain: tiles resident
#pragma unroll
        for (int ks = 0; ks < 2; ks++) {
            half8 af[4], bw[4];
#pragma unroll
            for (int i = 0; i < 4; i++) {
                const int ar = wm * 64 + i * 16 + (lane & 15);
                const int brw = wn * 64 + i * 16 + (lane & 15);
                const int cc = (ks * 64 + (lane >> 4) * 16) ^ ((lane & 7) << 4);
                af[i] = *(const half8*)((const char*)As + ar * 128 + cc);
                bw[i] = *(const half8*)((const char*)Bs + brw * 128 + cc);
            }
#pragma unroll
            for (int i = 0; i < 4; i++)
#pragma unroll
                for (int j = 0; j < 4; j++)
                    acc[i][j] = __builtin_amdgcn_mfma_f32_16x16x32_f16(af[i], bw[j], acc[i][j], 0, 0, 0);
        }
        __syncthreads();   // tiles consumed before next stage overwrites
    }
    f16* __restrict__ gid = gi + (size_t)dir * NM * NH3;
#pragma unroll
    for (int i = 0; i < 4; i++) {
        const int m = m0 + wm * 64 + i * 16 + ((lane >> 4) << 2);
#pragma unroll
        for (int j = 0; j < 4; j++) {
            const int n = n0 + wn * 64 + j * 16 + (lane & 15);
            const float b = bias[n];
#pragma unroll
            for (int r = 0; r < 4; r++)
                gid[(size_t)(m + r) * NH3 + n] = (f16)(acc[i][j][r] + b);
        }
    }
}

// ---------------- device-coherent helpers ----------------
__device__ __forceinline__ unsigned long long ld_dev_u64(const void* p) {
    return __hip_atomic_load((const unsigned long long*)p,
                             __ATOMIC_RELAXED, __HIP_MEMORY_SCOPE_AGENT);
}
__device__ __forceinline__ void st_dev_u64(void* p, unsigned long long v) {
    __hip_atomic_store((unsigned long long*)p, v,
                       __ATOMIC_RELAXED, __HIP_MEMORY_SCOPE_AGENT);
}

union U2H8 { unsigned long long u[2]; half8 h; };

// ---------------- GRU scan (R11/R14, byte-identical — proven optimum) ----------------
// 64 blocks (blockIdx/32 = dir, blockIdx%32 = 16-col slice), 128 threads (2 waves).
// TRANSPOSED MFMA: A-operand = W rows (16 output cols), B-operand = h (16 batches)
// -> each lane owns 4 CONSECUTIVE output cols x 1 batch = exactly one u64 of 4 f16:
// publish = single coherent store, no LDS transpose, no barrier. Tag = 2 stolen LSBs
// (mod-4 generation; only possible stale occupant is gen t-2, differing in bit16).
// Consumer fragments are a zero-ALU bitcast of 2 u64s; detection completes WITH the
// data in registers (1 coherent RT).
__global__ __launch_bounds__(128, 1) void gru_scan(
    const f16* __restrict__ gi,      // [2][NM][1536]
    const f16* __restrict__ Whf, const f16* __restrict__ Whr,   // [1536][512]
    const float* __restrict__ bhf, const float* __restrict__ bhr,
    unsigned long long* __restrict__ HB,   // [2][2][32][128] u64
    f16* __restrict__ y16,           // layer0 output (fp16) or nullptr
    float* __restrict__ y32,         // layer1 output (fp32, d_out) or nullptr
    float* __restrict__ hlast)       // [2][NB][NH] fp32
{
    __shared__ f16 Wlds[48 * 520];
    const int d = blockIdx.x >> 5;
    const int cs = blockIdx.x & 31;
    const int c0 = cs * 16;
    const f16* __restrict__ W = d ? Whr : Whf;
    const float* __restrict__ bhh = d ? bhr : bhf;
    const int tid = threadIdx.x;
    const int lane = tid & 63;
    const int mt = tid >> 6;         // wave index = batch half

    // stage W_hh rows {g*512 + c0 + j} into LDS (row-major [48][520], padded)
    for (int c = tid; c < 48 * 64; c += 128) {
        const int row = c >> 6;
        const int off = (c & 63) * 8;
        const int g = row >> 4, j = row & 15;
        *(int4*)(Wlds + row * 520 + off) = *(const int4*)(W + (size_t)(g * 512 + c0 + j) * 512 + off);
    }
    __syncthreads();

    // W fragments (A-operand): lane holds W[c0 + (lane&15)][k-slice]
    half8 bfr[16][3];
#pragma unroll
    for (int kk = 0; kk < 16; kk++)
#pragma unroll
        for (int g = 0; g < 3; g++)
            bfr[kk][g] = *(const half8*)(Wlds + (g * 16 + (lane & 15)) * 520 + kk * 32 + (lane >> 4) * 8);

    const int bP = mt * 16 + (lane & 15);   // owned batch (B-col = C-col)
    const int q  = lane >> 4;               // col-quad 0..3
    const int cP = c0 + q * 4;              // first owned output col (C-rows q*4+r)

    float bh[3][4];
#pragma unroll
    for (int g = 0; g < 3; g++) {
        const float4v bv = *(const float4v*)(bhh + g * 512 + cP);
#pragma unroll
        for (int r = 0; r < 4; r++) bh[g][r] = bv[r];
    }

    const f16* __restrict__ giD = gi + (size_t)d * NM * NH3;
    unsigned long long* const HBd = HB + (size_t)d * 2 * 32 * 128;

    float h32[4] = {0.f, 0.f, 0.f, 0.f};
    float gif[3][4];
    {
        const int te = d ? (NT - 1) : 0;
        const f16* p = giD + ((size_t)bP * NT + te) * NH3 + cP;
#pragma unroll
        for (int g = 0; g < 3; g++) {
            const half4v v = *(const half4v*)(p + g * 512);
#pragma unroll
            for (int r = 0; r < 4; r++) gif[g][r] = (float)v[r];
        }
    }

    for (int t = 0; t < NT; t++) {
        const int te = d ? (NT - 1 - t) : t;
        const unsigned long long* const HBr =
            HBd + (size_t)(t & 1) * 32 * 128 + (size_t)bP * 128;
        const unsigned long long tagpat =
            (unsigned long long)((unsigned)(t & 1)) |
            ((unsigned long long)((unsigned)((t >> 1) & 1)) << 16);

        // -------- poll: 32 u64 (own batch row) until all tag bits match gen t ------
        unsigned long long ch[16][2];
        bool ok;
        do {
#pragma unroll
            for (int kk = 0; kk < 16; kk++) {
                ch[kk][0] = ld_dev_u64(HBr + kk * 8 + q * 2);
                ch[kk][1] = ld_dev_u64(HBr + kk * 8 + q * 2 + 1);
            }
            unsigned long long bad = 0;
#pragma unroll
            for (int kk = 0; kk < 16; kk++)
#pragma unroll
                for (int c = 0; c < 2; c++)
                    bad |= (ch[kk][c] ^ tagpat) & 0x0000000000010001ull;
            ok = __all(bad == 0);
        } while (!ok);

        // -------- fragments (zero-ALU bitcast) + transposed MFMA --------
        float4v acc[3] = {};
#pragma unroll
        for (int kk = 0; kk < 16; kk++) {
            U2H8 u;
            u.u[0] = ch[kk][0];
            u.u[1] = ch[kk][1];
#pragma unroll
            for (int g = 0; g < 3; g++)
                acc[g] = __builtin_amdgcn_mfma_f32_16x16x32_f16(bfr[kk][g], u.h, acc[g], 0, 0, 0);
        }

        float hnew[4]; f16 hnew16[4];
#pragma unroll
        for (int r = 0; r < 4; r++) {
            const float hr = acc[0][r] + bh[0][r];
            const float hz = acc[1][r] + bh[1][r];
            const float hn = acc[2][r] + bh[2][r];
            const float rg = 1.f / (1.f + __expf(-(gif[0][r] + hr)));
            const float zg = 1.f / (1.f + __expf(-(gif[1][r] + hz)));
            const float x2 = gif[2][r] + rg * hn;
            const float e2 = __expf(x2 + x2);
            const float ng = 1.f - 2.f / (e2 + 1.f);
            const float h = (1.f - zg) * ng + zg * h32[r];
            h32[r] = h; hnew[r] = h; hnew16[r] = (f16)h;
        }

        const bool more = (t + 1 < NT);
        if (more) {
            // -------- publish: ONE tagged u64 store per thread, immediately --------
            unsigned long long pk =
                (unsigned long long)__builtin_bit_cast(unsigned short, hnew16[0]) |
                ((unsigned long long)__builtin_bit_cast(unsigned short, hnew16[1]) << 16) |
                ((unsigned long long)__builtin_bit_cast(unsigned short, hnew16[2]) << 32) |
                ((unsigned long long)__builtin_bit_cast(unsigned short, hnew16[3]) << 48);
            pk = (pk & ~0x0000000000010001ull) |
                 (unsigned long long)((unsigned)((t + 1) & 1)) |
                 ((unsigned long long)((unsigned)(((t + 1) >> 1) & 1)) << 16);
            st_dev_u64(HBd + (size_t)((t + 1) & 1) * 32 * 128 + (size_t)bP * 128 + (cP >> 2), pk);
        }
        // -------- y output (clean values, vectorized nontemporal) --------
        {
            const size_t yoff = ((size_t)bP * NT + te) * (2 * NH) + d * NH + cP;
            if (y16) {
                const unsigned long long yv =
                    (unsigned long long)__builtin_bit_cast(unsigned short, hnew16[0]) |
                    ((unsigned long long)__builtin_bit_cast(unsigned short, hnew16[1]) << 16) |
                    ((unsigned long long)__builtin_bit_cast(unsigned short, hnew16[2]) << 32) |
                    ((unsigned long long)__builtin_bit_cast(unsigned short, hnew16[3]) << 48);
                __builtin_nontemporal_store(yv, (unsigned long long*)(y16 + yoff));
            } else {
                float4v yv; yv[0] = hnew[0]; yv[1] = hnew[1]; yv[2] = hnew[2]; yv[3] = hnew[3];
                __builtin_nontemporal_store(yv, (float4v*)(y32 + yoff));
            }
        }
        if (t == NT - 1) {
            float4v hv; hv[0] = hnew[0]; hv[1] = hnew[1]; hv[2] = hnew[2]; hv[3] = hnew[3];
            *(float4v*)(hlast + d * NB * NH + bP * NH + cP) = hv;
        }
        if (more) {
            // prefetch gi for t+1 (plain cached; in flight during next poll)
            const int te2 = d ? (NT - 2 - t) : (t + 1);
            const f16* p = giD + ((size_t)bP * NT + te2) * NH3 + cP;
#pragma unroll
            for (int g = 0; g < 3; g++) {
                const half4v v = *(const half4v*)(p + g * 512);
#pragma unroll
                for (int r = 0; r < 4; r++) gif[g][r] = (float)v[r];
            }
        }
    }
}

extern "C" void kernel_launch(void* const* d_in, const int* in_sizes, int n_in,
                              void* d_out, int out_size, void* d_ws, size_t ws_size,
                              hipStream_t stream) {
    (void)in_sizes; (void)n_in; (void)out_size; (void)ws_size;
    const float* X     = (const float*)d_in[0];
    const float* wih0f = (const float*)d_in[1];
    const float* bih0f = (const float*)d_in[2];
    const float* whh0f = (const float*)d_in[3];
    const float* bhh0f = (const float*)d_in[4];
    const float* wih0r = (const float*)d_in[5];
    const float* bih0r = (const float*)d_in[6];
    const float* whh0r = (const float*)d_in[7];
    const float* bhh0r = (const float*)d_in[8];
    const float* wih1f = (const float*)d_in[9];
    const float* bih1f = (const float*)d_in[10];
    const float* whh1f = (const float*)d_in[11];
    const float* bhh1f = (const float*)d_in[12];
    const float* wih1r = (const float*)d_in[13];
    const float* bih1r = (const float*)d_in[14];
    const float* whh1r = (const float*)d_in[15];
    const float* bhh1r = (const float*)d_in[16];

    char* ws = (char*)d_ws;
    f16* Xh   = (f16*)(ws + 0ull);
    f16* Wi0f = (f16*)(ws + 33554432ull);
    f16* Wi0r = (f16*)(ws + 35127296ull);
    f16* Wh0f = (f16*)(ws + 36700160ull);
    f16* Wh0r = (f16*)(ws + 38273024ull);
    f16* Wi1f = (f16*)(ws + 39845888ull);
    f16* Wi1r = (f16*)(ws + 42991616ull);
    f16* Wh1f = (f16*)(ws + 46137344ull);
    f16* Wh1r = (f16*)(ws + 47710208ull);
    f16* Y0h  = (f16*)(ws + 49283072ull);
    unsigned long long* HBu = (unsigned long long*)(ws + 116391936ull);  // 128KB
    f16* GI   = (f16*)(ws + 116655104ull);
    float* out = (float*)d_out;

    auto cvt = [&](const float* s, f16* d, size_t n) {
        int n4 = (int)(n / 4);
        int grid = (n4 + 255) / 256; if (grid > 4096) grid = 4096;
        cvt_f16<<<grid, 256, 0, stream>>>(s, d, n4);
    };
    cvt(X,     Xh,   (size_t)NM * NH);
    cvt(wih0f, Wi0f, (size_t)NH3 * NH);
    cvt(wih0r, Wi0r, (size_t)NH3 * NH);
    cvt(whh0f, Wh0f, (size_t)NH3 * NH);
    cvt(whh0r, Wh0r, (size_t)NH3 * NH);
    cvt(wih1f, Wi1f, (size_t)NH3 * 2 * NH);
    cvt(wih1r, Wi1r, (size_t)NH3 * 2 * NH);
    cvt(whh1f, Wh1f, (size_t)NH3 * NH);
    cvt(whh1r, Wh1r, (size_t)NH3 * NH);

    const size_t OUT0 = (size_t)NM * 2 * NH;   // 33,554,432 floats

    // Layer 0
    init_hb<<<64, 256, 0, stream>>>(HBu);
    gemm_gi<<<dim3(NM / 128, 24), 256, 0, stream>>>(Xh, Wi0f, Wi0r, bih0f, bih0r, GI, NH);
    gru_scan<<<64, 128, 0, stream>>>(GI, Wh0f, Wh0r, bhh0f, bhh0r,
                                     HBu, Y0h, nullptr, out + OUT0);
    // Layer 1 (reset tags to gen 0, reuse HB)
    init_hb<<<64, 256, 0, stream>>>(HBu);
    gemm_gi<<<dim3(NM / 128, 24), 256, 0, stream>>>(Y0h, Wi1f, Wi1r, bih1f, bih1r, GI, 2 * NH);
    gru_scan<<<64, 128, 0, stream>>>(GI, Wh1f, Wh1r, bhh1f, bhh1r,
                                     HBu, nullptr, out, out + OUT0 + 2 * NB * NH);
}